// Round 1
// baseline (370.425 us; speedup 1.0000x reference)
//
#include <hip/hip_runtime.h>
#include <hip/hip_bf16.h>

// Problem dims (fixed by setup_inputs)
#define NB 32
#define CC 1024
#define SS 1568            // T*H*W = 32*7*7
#define KK 128
#define SB 14              // s-blocks per n
#define BN 112             // columns per s-block (14*112 = 1568, no tail)
#define NCOL (NB*SB)       // 448 bn6 partial columns
#define EPSV 1e-5f

typedef __attribute__((ext_vector_type(8))) short bf16x8;
typedef __attribute__((ext_vector_type(4))) short bf16x4v;
typedef __attribute__((ext_vector_type(4))) float f32x4;

__device__ __forceinline__ unsigned short f2bf(float f) {
  union { float f; unsigned u; } v; v.f = f;
  return (unsigned short)((v.u + 0x7fffu + ((v.u >> 16) & 1u)) >> 16);
}

// ---------------- bn1: per-channel stats of x over (n,t,h,w) ----------------
__global__ void bn1_part(const float* __restrict__ x, float* __restrict__ part1) {
  int bid = blockIdx.x;              // NB*CC blocks, 64 threads
  int c = bid >> 5, n = bid & 31;
  const float4* p = (const float4*)(x + (size_t)(n * CC + c) * SS);
  int t = threadIdx.x;
  float s = 0.f, sq = 0.f;
  for (int i = t; i < SS / 4; i += 64) {
    float4 v = p[i];
    s  += v.x + v.y + v.z + v.w;
    sq += v.x * v.x + v.y * v.y + v.z * v.z + v.w * v.w;
  }
  for (int m = 1; m < 64; m <<= 1) { s += __shfl_xor(s, m); sq += __shfl_xor(sq, m); }
  if (t == 0) { part1[(c * NB + n) * 2] = s; part1[(c * NB + n) * 2 + 1] = sq; }
}

__global__ void bn1_fin(const float* __restrict__ part1, const float* __restrict__ g1,
                        const float* __restrict__ b1, float* a1, float* c1) {
  int c = blockIdx.x * 256 + threadIdx.x;
  float s = 0.f, sq = 0.f;
  for (int n = 0; n < NB; n++) { s += part1[(c * NB + n) * 2]; sq += part1[(c * NB + n) * 2 + 1]; }
  float inv = 1.f / ((float)NB * SS);
  float m = s * inv, var = sq * inv - m * m;
  float r = rsqrtf(var + EPSV);
  float a = g1[c] * r;
  a1[c] = a; c1[c] = b1[c] - m * a;
}

// ---------------- bn2: per-channel stats of nodes over K ----------------
__global__ void bn2_fin(const float* __restrict__ nodes, const float* __restrict__ g2,
                        const float* __restrict__ b2, float* a2, float* c2) {
  int c = blockIdx.x * 256 + threadIdx.x;
  float s = 0.f, sq = 0.f;
  for (int k = 0; k < KK; k++) { float v = nodes[k * CC + c]; s += v; sq += v * v; }
  float inv = 1.f / (float)KK;
  float m = s * inv, var = sq * inv - m * m;
  float r = rsqrtf(var + EPSV);
  float a = g2[c] * r;
  a2[c] = a; c2[c] = b2[c] - m * a;
}

// ---------------- linear: L[k][j] = sum_c nhat[k][c]*W[j][c] + bW[j] ----------------
__global__ void node_linear(const float* __restrict__ nodes, const float* __restrict__ a2,
                            const float* __restrict__ c2, const float* __restrict__ Wm,
                            const float* __restrict__ bW, float* __restrict__ Lb) {
  __shared__ float An[8][CC];        // 32 KB
  int kt = blockIdx.x;               // 16
  int jt = blockIdx.y;               // 4
  int t = threadIdx.x;
  for (int r = 0; r < 8; r++)
    for (int i = t; i < CC; i += 256)
      An[r][i] = nodes[(size_t)(kt * 8 + r) * CC + i] * a2[i] + c2[i];
  __syncthreads();
  int j = jt * 256 + t;
  float acc[8];
  float bw = bW[j];
  #pragma unroll
  for (int r = 0; r < 8; r++) acc[r] = bw;
  const float* wr = Wm + (size_t)j * CC;
  for (int c = 0; c < CC; c++) {
    float w = wr[c];
    #pragma unroll
    for (int r = 0; r < 8; r++) acc[r] += An[r][c] * w;
  }
  for (int r = 0; r < 8; r++) Lb[(size_t)(kt * 8 + r) * CC + j] = acc[r];
}

// ---------------- bn3 per-row + pack ndA (K x C) and Mt (C x K, gate folded) ----------------
__global__ void bn3_pack(const float* __restrict__ Lb, const float* __restrict__ g3,
                         const float* __restrict__ b3, const float* __restrict__ loc,
                         unsigned short* __restrict__ ndA, unsigned short* __restrict__ Mt) {
  __shared__ float red[8];
  int k = blockIdx.x, t = threadIdx.x;
  float vv[4];
  float s = 0.f, sq = 0.f;
  for (int i = 0; i < 4; i++) {
    float v = Lb[(size_t)k * CC + t + 256 * i];
    vv[i] = v; s += v; sq += v * v;
  }
  for (int m = 1; m < 64; m <<= 1) { s += __shfl_xor(s, m); sq += __shfl_xor(sq, m); }
  int w = t >> 6;
  if ((t & 63) == 0) { red[w] = s; red[4 + w] = sq; }
  __syncthreads();
  s  = red[0] + red[1] + red[2] + red[3];
  sq = red[4] + red[5] + red[6] + red[7];
  float inv = 1.f / (float)CC;
  float m3 = s * inv, var = sq * inv - m3 * m3;
  float r = rsqrtf(var + EPSV);
  float a = g3[k] * r, cc = b3[k] - m3 * a;
  float lv = loc[0];
  float gate = 1.f / (1.f + __expf(-lv)) * 1.2f - 0.1f;
  gate = fminf(fmaxf(gate, 0.f), 1.f);
  for (int i = 0; i < 4; i++) {
    int j = t + 256 * i;
    float nd = vv[i] * a + cc;
    ndA[(size_t)k * CC + j] = f2bf(nd);
    Mt[(size_t)j * KK + k] = f2bf(gate * nd);
  }
}

// ---------------- GEMM1: G[n][s][k] = sum_c xhat[n][c][s] * nd[k][c]  (G stored [s][k]) ----------------
__global__ __launch_bounds__(256) void gemm1(
    const float* __restrict__ x, const float* __restrict__ a1, const float* __restrict__ c1,
    const unsigned short* __restrict__ ndA, unsigned short* __restrict__ GT) {
  __shared__ __align__(16) unsigned short Bt[BN][72];  // pitch 72 bf16 = 144B (4-bank row stride)
  __shared__ float a1s[CC], c1s[CC];
  int sb = blockIdx.x;               // 14
  int n  = blockIdx.y;               // 32
  int t = threadIdx.x;
  int w = t >> 6, lane = t & 63;
  int g = lane >> 4, l15 = lane & 15;
  for (int i = t; i < CC; i += 256) { a1s[i] = a1[i]; c1s[i] = c1[i]; }
  f32x4 acc[2][7];
  for (int m = 0; m < 2; m++)
    for (int nf = 0; nf < 7; nf++) acc[m][nf] = (f32x4){0.f, 0.f, 0.f, 0.f};
  int s0 = sb * BN;
  const float* xn = x + (size_t)n * CC * SS;
  bool act = t < 224;
  int ss  = act ? (t % BN) : 0;
  int cg0 = act ? (t / BN) : 0;
  __syncthreads();                   // a1s/c1s ready
  for (int c0 = 0; c0 < CC; c0 += 64) {
    if (act) {
      #pragma unroll
      for (int it = 0; it < 4; ++it) {
        int cg = cg0 + 2 * it;       // 0..7
        int cb = c0 + cg * 8;
        bf16x8 pk;
        #pragma unroll
        for (int jj = 0; jj < 8; jj++) {
          int c = cb + jj;
          float v = xn[(size_t)c * SS + s0 + ss];   // lanes span consecutive s -> coalesced
          pk[jj] = (short)f2bf(v * a1s[c] + c1s[c]);
        }
        *(bf16x8*)&Bt[ss][cg * 8] = pk;
      }
    }
    __syncthreads();
    const unsigned short* Ab = ndA + (size_t)(w * 32) * CC + c0;
    #pragma unroll
    for (int ks = 0; ks < 2; ks++) {
      bf16x8 af[2];
      #pragma unroll
      for (int m = 0; m < 2; m++)
        af[m] = *(const bf16x8*)(Ab + (size_t)(m * 16 + l15) * CC + ks * 32 + g * 8);
      #pragma unroll
      for (int nf = 0; nf < 7; nf++) {
        bf16x8 bfr = *(const bf16x8*)&Bt[nf * 16 + l15][ks * 32 + g * 8];
        #pragma unroll
        for (int m = 0; m < 2; m++)
          acc[m][nf] = __builtin_amdgcn_mfma_f32_16x16x32_bf16(af[m], bfr, acc[m][nf], 0, 0, 0);
      }
    }
    __syncthreads();
  }
  // epilogue: GT[n][s][k], k contiguous (reg index = consecutive k)
  unsigned short* gtn = GT + (size_t)n * SS * KK;
  #pragma unroll
  for (int nf = 0; nf < 7; nf++) {
    int s = s0 + nf * 16 + l15;
    #pragma unroll
    for (int m = 0; m < 2; m++) {
      int k = w * 32 + m * 16 + g * 4;
      bf16x4v ov;
      #pragma unroll
      for (int r = 0; r < 4; r++) ov[r] = (short)f2bf(acc[m][nf][r]);
      *(bf16x4v*)(gtn + (size_t)s * KK + k) = ov;
    }
  }
}

// ---------------- GEMM2: Y[n][c][s] = sum_k Mt[c][k] * G[n][s][k]; fused bn6 partials ----------------
__global__ __launch_bounds__(256) void gemm2(
    const unsigned short* __restrict__ Mt, const unsigned short* __restrict__ GT,
    float* __restrict__ y, float* __restrict__ psum, float* __restrict__ psq) {
  int ct = blockIdx.x;               // 8
  int sb = blockIdx.y;               // 14
  int n  = blockIdx.z;               // 32
  int t = threadIdx.x, w = t >> 6, lane = t & 63;
  int g = lane >> 4, l15 = lane & 15;
  int s0 = sb * BN;
  f32x4 acc[2][7];
  for (int m = 0; m < 2; m++)
    for (int nf = 0; nf < 7; nf++) acc[m][nf] = (f32x4){0.f, 0.f, 0.f, 0.f};
  const unsigned short* gtb = GT + ((size_t)n * SS + s0) * KK;
  const unsigned short* mtb = Mt + (size_t)(ct * 128 + w * 32) * KK;
  #pragma unroll
  for (int ks = 0; ks < 4; ks++) {
    bf16x8 af[2];
    #pragma unroll
    for (int m = 0; m < 2; m++)
      af[m] = *(const bf16x8*)(mtb + (size_t)(m * 16 + l15) * KK + ks * 32 + g * 8);
    #pragma unroll
    for (int nf = 0; nf < 7; nf++) {
      bf16x8 bfr = *(const bf16x8*)(gtb + (size_t)(nf * 16 + l15) * KK + ks * 32 + g * 8);
      #pragma unroll
      for (int m = 0; m < 2; m++)
        acc[m][nf] = __builtin_amdgcn_mfma_f32_16x16x32_bf16(af[m], bfr, acc[m][nf], 0, 0, 0);
    }
  }
  float rs[2][4], rq[2][4];
  for (int m = 0; m < 2; m++)
    for (int r = 0; r < 4; r++) { rs[m][r] = 0.f; rq[m][r] = 0.f; }
  float* yn = y + ((size_t)n * CC + ct * 128) * SS;
  #pragma unroll
  for (int nf = 0; nf < 7; nf++) {
    int s = s0 + nf * 16 + l15;
    #pragma unroll
    for (int m = 0; m < 2; m++) {
      int rowb = w * 32 + m * 16 + g * 4;
      #pragma unroll
      for (int r = 0; r < 4; r++) {
        float v = acc[m][nf][r];
        yn[(size_t)(rowb + r) * SS + s] = v;
        rs[m][r] += v; rq[m][r] += v * v;
      }
    }
  }
  #pragma unroll
  for (int m = 0; m < 2; m++)
    #pragma unroll
    for (int r = 0; r < 4; r++) {
      float a = rs[m][r], b = rq[m][r];
      for (int msk = 1; msk < 16; msk <<= 1) { a += __shfl_xor(a, msk); b += __shfl_xor(b, msk); }
      if (l15 == 0) {
        int c = ct * 128 + w * 32 + m * 16 + g * 4 + r;
        int col = n * SB + sb;
        psum[(size_t)col * CC + c] = a;
        psq[(size_t)col * CC + c]  = b;
      }
    }
}

__global__ void bn6_fin(const float* __restrict__ psum, const float* __restrict__ psq,
                        const float* __restrict__ g6, const float* __restrict__ b6,
                        float* a6, float* c6) {
  int c = blockIdx.x * 256 + threadIdx.x;
  float s = 0.f, sq = 0.f;
  for (int i = 0; i < NCOL; i++) { s += psum[(size_t)i * CC + c]; sq += psq[(size_t)i * CC + c]; }
  float inv = 1.f / ((float)NB * SS);
  float m = s * inv, var = sq * inv - m * m;
  float r = rsqrtf(var + EPSV);
  float a = g6[c] * r;
  a6[c] = a; c6[c] = b6[c] - m * a;
}

__global__ void bn6_leaky(float* __restrict__ y, const float* __restrict__ a6,
                          const float* __restrict__ c6) {
  size_t total = (size_t)NB * CC * SS / 4;
  float4* p = (float4*)y;
  for (size_t i = (size_t)blockIdx.x * blockDim.x + threadIdx.x; i < total;
       i += (size_t)gridDim.x * blockDim.x) {
    int c = (int)((i / (SS / 4)) & (CC - 1));
    float a = a6[c], cc = c6[c];
    float4 v = p[i];
    float x0 = v.x * a + cc, x1 = v.y * a + cc, x2 = v.z * a + cc, x3 = v.w * a + cc;
    v.x = x0 >= 0.f ? x0 : 0.2f * x0;
    v.y = x1 >= 0.f ? x1 : 0.2f * x1;
    v.z = x2 >= 0.f ? x2 : 0.2f * x2;
    v.w = x3 >= 0.f ? x3 : 0.2f * x3;
    p[i] = v;
  }
}

extern "C" void kernel_launch(void* const* d_in, const int* in_sizes, int n_in,
                              void* d_out, int out_size, void* d_ws, size_t ws_size,
                              hipStream_t stream) {
  const float* x     = (const float*)d_in[0];
  const float* nodes = (const float*)d_in[1];
  const float* g1 = (const float*)d_in[2];
  const float* b1 = (const float*)d_in[3];
  const float* g2 = (const float*)d_in[4];
  const float* b2 = (const float*)d_in[5];
  const float* g3 = (const float*)d_in[6];
  const float* b3 = (const float*)d_in[7];
  const float* Wm = (const float*)d_in[8];
  const float* bW = (const float*)d_in[9];
  const float* loc = (const float*)d_in[10];
  const float* g6 = (const float*)d_in[11];
  const float* b6 = (const float*)d_in[12];
  float* y = (float*)d_out;
  char* ws = (char*)d_ws;
  // ws layout (bytes), ~17.9 MB total
  float* part1 = (float*)(ws + 0);               // 262144
  float* a1 = (float*)(ws + 262144);
  float* c1 = (float*)(ws + 266240);
  float* a2 = (float*)(ws + 270336);
  float* c2 = (float*)(ws + 274432);
  float* Lb = (float*)(ws + 278528);             // 512 KB
  unsigned short* ndA = (unsigned short*)(ws + 802816);   // 256 KB
  unsigned short* Mt  = (unsigned short*)(ws + 1064960);  // 256 KB
  float* a6 = (float*)(ws + 1327104);
  float* c6 = (float*)(ws + 1331200);
  float* psum = (float*)(ws + 1335296);          // 448*1024*4
  float* psq  = (float*)(ws + 3170304);
  unsigned short* GT = (unsigned short*)(ws + 5005312);   // 12.85 MB

  bn1_part<<<dim3(NB * CC), dim3(64), 0, stream>>>(x, part1);
  bn1_fin<<<dim3(4), dim3(256), 0, stream>>>(part1, g1, b1, a1, c1);
  bn2_fin<<<dim3(4), dim3(256), 0, stream>>>(nodes, g2, b2, a2, c2);
  node_linear<<<dim3(16, 4), dim3(256), 0, stream>>>(nodes, a2, c2, Wm, bW, Lb);
  bn3_pack<<<dim3(KK), dim3(256), 0, stream>>>(Lb, g3, b3, loc, ndA, Mt);
  gemm1<<<dim3(SB, NB), dim3(256), 0, stream>>>(x, a1, c1, ndA, GT);
  gemm2<<<dim3(8, SB, NB), dim3(256), 0, stream>>>(Mt, GT, y, psum, psq);
  bn6_fin<<<dim3(4), dim3(256), 0, stream>>>(psum, psq, g6, b6, a6, c6);
  bn6_leaky<<<dim3(8192), dim3(256), 0, stream>>>(y, a6, c6);
}